// Round 3
// baseline (300.852 us; speedup 1.0000x reference)
//
#include <hip/hip_runtime.h>
#include <stdint.h>

#define B_SZ 8192
#define N_F 12
#define H_DIM 512
#define K_DIM 1024
#define V_DIM 256

typedef __attribute__((ext_vector_type(8))) __bf16 bf16x8;
typedef __attribute__((ext_vector_type(4))) float f32x4;

// tanh-approx GELU in sigmoid form; |err| vs exact erf-GELU ~1e-3 << 4.6e-2.
__device__ inline float gelu_f(float x) {
  float t = 1.5957691216057308f * x * (1.0f + 0.044715f * x * x);
  return x / (1.0f + __expf(-t));
}

__device__ inline void gld_lds16(const void* g, void* l) {
  __builtin_amdgcn_global_load_lds(
      (const __attribute__((address_space(1))) void*)g,
      (__attribute__((address_space(3))) void*)l, 16, 0, 0);
}

// ---------------------------------------------------------------------------
// Kernel 1: wave-per-row. Lane l owns dims [l*8, l*8+8) of H=512.
// Emits the FULL K=1024 activation row per n. act2 layout: [N][B][K] bf16,
// 16B-chunk XOR swizzle within each 64-elem K-group (chunk c at c^(b&7)) so
// k_gemm's contiguous global_load_lds staging lands conflict-free in LDS.
// ---------------------------------------------------------------------------
__global__ __launch_bounds__(256, 4) void k_prep(
    const float* __restrict__ ie, const int* __restrict__ feat,
    const float* __restrict__ tab, const float* __restrict__ gam,
    const float* __restrict__ bet, __bf16* __restrict__ act2) {
  const int lane = threadIdx.x & 63;
  const int b = blockIdx.x * 4 + (threadIdx.x >> 6);

  const float* cb = ie + (size_t)b * H_DIM + lane * 8;
  float4 c0 = *(const float4*)cb;
  float4 c1 = *(const float4*)(cb + 4);
  float s = c0.x + c0.y + c0.z + c0.w + c1.x + c1.y + c1.z + c1.w;
  float q = c0.x * c0.x + c0.y * c0.y + c0.z * c0.z + c0.w * c0.w +
            c1.x * c1.x + c1.y * c1.y + c1.z * c1.z + c1.w * c1.w;
#pragma unroll
  for (int o = 1; o < 64; o <<= 1) {
    s += __shfl_xor(s, o, 64);
    q += __shfl_xor(q, o, 64);
  }
  const float S1 = s, Q1 = q;

  const float4 gl0 = *(const float4*)(gam + lane * 8);
  const float4 gl1 = *(const float4*)(gam + lane * 8 + 4);
  const float4 el0 = *(const float4*)(bet + lane * 8);
  const float4 el1 = *(const float4*)(bet + lane * 8 + 4);
  const float4 g0 = *(const float4*)(gam + H_DIM + lane * 8);
  const float4 g1 = *(const float4*)(gam + H_DIM + lane * 8 + 4);
  const float4 e0 = *(const float4*)(bet + H_DIM + lane * 8);
  const float4 e1 = *(const float4*)(bet + H_DIM + lane * 8 + 4);

  float r[8];
#pragma unroll
  for (int i = 0; i < 8; ++i) r[i] = 0.f;

  const int sw = (lane & ~7) | ((lane & 7) ^ (b & 7));
  __bf16* arow = act2 + (size_t)b * K_DIM + sw * 8;

  for (int n = 0; n < N_F; ++n) {
    s = 0.f; q = 0.f;
#pragma unroll
    for (int i = 0; i < 8; ++i) { s += r[i]; q += r[i] * r[i]; }
#pragma unroll
    for (int o = 1; o < 64; o <<= 1) {
      s += __shfl_xor(s, o, 64);
      q += __shfl_xor(q, o, 64);
    }
    const float mean = (S1 + s) * (1.0f / 1024.0f);
    const float var = (Q1 + q) * (1.0f / 1024.0f) - mean * mean;
    const float rs = rsqrtf(var + 1e-5f);

    // issue next gather early so HBM/L2 latency hides under the gelu work
    float4 t0, t1;
    const bool have = (n < N_F - 1);
    if (have) {
      const int f = feat[b * N_F + n];
      const float* tr = tab + ((size_t)n * V_DIM + f) * H_DIM + lane * 8;
      t0 = *(const float4*)tr;
      t1 = *(const float4*)(tr + 4);
    }

    // ctx half (k in [0,512))
    bf16x8 pc;
    pc[0] = (__bf16)gelu_f((c0.x - mean) * rs * gl0.x + el0.x);
    pc[1] = (__bf16)gelu_f((c0.y - mean) * rs * gl0.y + el0.y);
    pc[2] = (__bf16)gelu_f((c0.z - mean) * rs * gl0.z + el0.z);
    pc[3] = (__bf16)gelu_f((c0.w - mean) * rs * gl0.w + el0.w);
    pc[4] = (__bf16)gelu_f((c1.x - mean) * rs * gl1.x + el1.x);
    pc[5] = (__bf16)gelu_f((c1.y - mean) * rs * gl1.y + el1.y);
    pc[6] = (__bf16)gelu_f((c1.z - mean) * rs * gl1.z + el1.z);
    pc[7] = (__bf16)gelu_f((c1.w - mean) * rs * gl1.w + el1.w);
    *(bf16x8*)(arow + (size_t)n * B_SZ * K_DIM) = pc;

    // masked-sums half (k in [512,1024))
    bf16x8 pk;
    pk[0] = (__bf16)gelu_f((r[0] - mean) * rs * g0.x + e0.x);
    pk[1] = (__bf16)gelu_f((r[1] - mean) * rs * g0.y + e0.y);
    pk[2] = (__bf16)gelu_f((r[2] - mean) * rs * g0.z + e0.z);
    pk[3] = (__bf16)gelu_f((r[3] - mean) * rs * g0.w + e0.w);
    pk[4] = (__bf16)gelu_f((r[4] - mean) * rs * g1.x + e1.x);
    pk[5] = (__bf16)gelu_f((r[5] - mean) * rs * g1.y + e1.y);
    pk[6] = (__bf16)gelu_f((r[6] - mean) * rs * g1.z + e1.z);
    pk[7] = (__bf16)gelu_f((r[7] - mean) * rs * g1.w + e1.w);
    *(bf16x8*)(arow + (size_t)n * B_SZ * K_DIM + H_DIM) = pk;

    if (have) {
      r[0] += t0.x; r[1] += t0.y; r[2] += t0.z; r[3] += t0.w;
      r[4] += t1.x; r[5] += t1.y; r[6] += t1.z; r[7] += t1.w;
    }
  }
}

// ---------------------------------------------------------------------------
// Kernel 2: pred_W [N][K][V] fp32 -> Wt [N][V][K] bf16, chunk-swizzled by v&7
// so that gld staging in k_gemm lands conflict-free in LDS.
// ---------------------------------------------------------------------------
__global__ __launch_bounds__(256) void k_wt(const float* __restrict__ W,
                                            __bf16* __restrict__ Wt) {
  __shared__ float tile[32][33];
  const int bid = blockIdx.x;
  const int n = bid >> 8;
  const int rem = bid & 255;
  const int kt = rem >> 3, vt = rem & 7;
  const int tx = threadIdx.x & 31, ty = threadIdx.x >> 5;
  const float* src = W + (size_t)n * K_DIM * V_DIM;
#pragma unroll
  for (int i = 0; i < 4; ++i) {
    const int k = kt * 32 + ty + i * 8;
    tile[ty + i * 8][tx] = src[(size_t)k * V_DIM + vt * 32 + tx];
  }
  __syncthreads();
  __bf16* dst = Wt + (size_t)n * V_DIM * K_DIM;
  const int t = threadIdx.x;
  if (t < 128) {
    const int v_l = t >> 2, c_l = t & 3;
    const int v = vt * 32 + v_l;
    bf16x8 pk;
#pragma unroll
    for (int e = 0; e < 8; ++e) pk[e] = (__bf16)tile[c_l * 8 + e][v_l];
    const int gc = kt * 4 + c_l;
    const int swc = (gc & ~7) | ((gc & 7) ^ (v & 7));
    *(bf16x8*)(dst + (size_t)v * K_DIM + swc * 8) = pk;
  }
}

// ---------------------------------------------------------------------------
// Kernel 3: pure GEMM, 3-buffer prefetch pipeline (T3+T4+T5).
// grid = (B/128, N), 512 threads (8 waves, 2x4), BM=128 BN=256 BK=64.
// LDS 144 KB (3 x 48 KB) -> 1 block/CU; latency hidden by the 2-deep
// prefetch, not TLP. One raw s_barrier per K-step; counted vmcnt(6)
// (= 6 gld_lds per wave per tile) so the in-flight tiles are never drained.
// Race safety: stage target buf[(kt+2)%3]==buf[(kt-1)%3]; every wave past
// barrier kt has consumed its kt-1 ds_reads (compiler lgkmcnt before MFMA),
// and in-order vmcnt completion makes vmcnt(6) guarantee tile kt landed.
// ---------------------------------------------------------------------------
__global__ __launch_bounds__(512, 2) void k_gemm(
    const __bf16* __restrict__ act2, const __bf16* __restrict__ Wt,
    const float* __restrict__ bias, float* __restrict__ out) {
  constexpr int BM = 128, BN = 256, BK = 64;
  __shared__ __align__(16) __bf16 As[3][BM * BK];  // 3 x 16 KB
  __shared__ __align__(16) __bf16 Ws[3][BN * BK];  // 3 x 32 KB (total 144 KB)

  const int n = blockIdx.y;
  const int b0 = blockIdx.x * BM;
  const int t = threadIdx.x;
  const int lane = t & 63;
  const int w = t >> 6;
  const int wm = w & 1;
  const int wn = w >> 1;
  const int l15 = lane & 15;
  const int lq = lane >> 4;
  const int lr8 = lane >> 3;
  const int lo8 = lane & 7;

  const __bf16* act2n = act2 + (size_t)n * B_SZ * K_DIM;
  const __bf16* Wtn = Wt + (size_t)n * V_DIM * K_DIM;

  f32x4 acc[4][4];
#pragma unroll
  for (int i = 0; i < 4; ++i)
#pragma unroll
    for (int j = 0; j < 4; ++j) acc[i][j] = (f32x4){0.f, 0.f, 0.f, 0.f};

  // 6 gld_lds16 per wave per tile (4 W + 2 A) -> vmcnt counts 6/tile.
  auto stage = [&](int buf, int kt) {
    const int k0 = kt * BK;
#pragma unroll
    for (int p = 0; p < 4; ++p) {
      const int v0 = w * 32 + p * 8;
      gld_lds16(Wtn + (size_t)(v0 + lr8) * K_DIM + k0 + lo8 * 8,
                &Ws[buf][v0 * BK]);
    }
#pragma unroll
    for (int p = 0; p < 2; ++p) {
      const int r0 = w * 16 + p * 8;
      gld_lds16(act2n + (size_t)(b0 + r0 + lr8) * K_DIM + k0 + lo8 * 8,
                &As[buf][r0 * BK]);
    }
  };

  auto compute = [&](int buf) {
    __builtin_amdgcn_s_setprio(1);
#pragma unroll
    for (int ks = 0; ks < 2; ++ks) {
      const int cs = ks * 4 + lq;  // 16B-chunk index within BK group
      bf16x8 af[4], bb[4];
#pragma unroll
      for (int i = 0; i < 4; ++i) {
        const int row = wm * 64 + i * 16 + l15;
        af[i] = *(const bf16x8*)(&As[buf][row * BK + ((cs ^ (row & 7)) << 3)]);
      }
#pragma unroll
      for (int j = 0; j < 4; ++j) {
        const int row = wn * 64 + j * 16 + l15;
        bb[j] = *(const bf16x8*)(&Ws[buf][row * BK + ((cs ^ (row & 7)) << 3)]);
      }
#pragma unroll
      for (int i = 0; i < 4; ++i)
#pragma unroll
        for (int j = 0; j < 4; ++j)
          acc[i][j] = __builtin_amdgcn_mfma_f32_16x16x32_bf16(af[i], bb[j],
                                                              acc[i][j], 0, 0, 0);
    }
    __builtin_amdgcn_s_setprio(0);
  };

  stage(0, 0);
  stage(1, 1);

#pragma unroll
  for (int kt = 0; kt < 14; ++kt) {
    // tile kt must have landed; tile kt+1's 6 glds may stay in flight.
    asm volatile("s_waitcnt vmcnt(6)" ::: "memory");
    __builtin_amdgcn_s_barrier();
    asm volatile("" ::: "memory");
    stage((kt + 2) % 3, kt + 2);
    compute(kt % 3);
  }
  // kt = 14: tile 15's glds still in flight
  asm volatile("s_waitcnt vmcnt(6)" ::: "memory");
  __builtin_amdgcn_s_barrier();
  asm volatile("" ::: "memory");
  compute(14 % 3);
  // kt = 15: drain
  asm volatile("s_waitcnt vmcnt(0)" ::: "memory");
  __builtin_amdgcn_s_barrier();
  asm volatile("" ::: "memory");
  compute(15 % 3);

  // epilogue: C/D layout col=lane&15, row=(lane>>4)*4+reg
#pragma unroll
  for (int j = 0; j < 4; ++j) {
    const int v = wn * 64 + j * 16 + l15;
    const float bv = bias[n * V_DIM + v];
#pragma unroll
    for (int i = 0; i < 4; ++i) {
      const int rb = wm * 64 + i * 16 + lq * 4;
#pragma unroll
      for (int r = 0; r < 4; ++r) {
        out[((size_t)(b0 + rb + r) * N_F + n) * V_DIM + v] = acc[i][j][r] + bv;
      }
    }
  }
}

// ---------------------------------------------------------------------------
extern "C" void kernel_launch(void* const* d_in, const int* in_sizes, int n_in,
                              void* d_out, int out_size, void* d_ws, size_t ws_size,
                              hipStream_t stream) {
  const float* ie = (const float*)d_in[0];
  const int* feat = (const int*)d_in[1];
  const float* tab = (const float*)d_in[2];
  const float* gam = (const float*)d_in[3];
  const float* bet = (const float*)d_in[4];
  const float* predW = (const float*)d_in[5];
  const float* predb = (const float*)d_in[6];
  float* out = (float*)d_out;

  char* ws = (char*)d_ws;
  __bf16* act2 = (__bf16*)ws;                        // 201,326,592 B
  __bf16* Wt = (__bf16*)(ws + 201326592);            //   6,291,456 B

  hipLaunchKernelGGL(k_prep, dim3(B_SZ / 4), dim3(256), 0, stream, ie, feat,
                     tab, gam, bet, act2);
  hipLaunchKernelGGL(k_wt, dim3(3072), dim3(256), 0, stream, predW, Wt);
  hipLaunchKernelGGL(k_gemm, dim3(B_SZ / 128, N_F), dim3(512), 0, stream,
                     act2, Wt, predb, out);
}

// Round 4
// 275.393 us; speedup vs baseline: 1.0924x; 1.0924x over previous
//
#include <hip/hip_runtime.h>
#include <stdint.h>

#define B_SZ 8192
#define N_F 12
#define H_DIM 512
#define K_DIM 1024
#define V_DIM 256

typedef __attribute__((ext_vector_type(8))) __bf16 bf16x8;
typedef __attribute__((ext_vector_type(4))) float f32x4;

// tanh-approx GELU in sigmoid form; |err| vs exact erf-GELU ~1e-3 << 4.6e-2.
__device__ inline float gelu_f(float x) {
  float t = 1.5957691216057308f * x * (1.0f + 0.044715f * x * x);
  return x / (1.0f + __expf(-t));
}

__device__ inline void gld_lds16(const void* g, void* l) {
  __builtin_amdgcn_global_load_lds(
      (const __attribute__((address_space(1))) void*)g,
      (__attribute__((address_space(3))) void*)l, 16, 0, 0);
}

// ---------------------------------------------------------------------------
// Kernel 1 (round-0 proven form): wave-per-row, masked-sums half only.
// Lane l owns dims [l*8, l*8+8). act2 [N][B][H=512] bf16, 16B-chunk XOR
// swizzle (chunk c at slot c^(b&7)). stats[b][n] = (mean, rsqrt).
// ---------------------------------------------------------------------------
__global__ __launch_bounds__(256, 8) void k_prep(
    const float* __restrict__ ie, const int* __restrict__ feat,
    const float* __restrict__ tab, const float* __restrict__ gam,
    const float* __restrict__ bet, __bf16* __restrict__ act2,
    float* __restrict__ stats) {
  const int lane = threadIdx.x & 63;
  const int b = blockIdx.x * 4 + (threadIdx.x >> 6);

  const float* cb = ie + (size_t)b * H_DIM + lane * 8;
  float4 c0 = *(const float4*)cb;
  float4 c1 = *(const float4*)(cb + 4);
  float s = c0.x + c0.y + c0.z + c0.w + c1.x + c1.y + c1.z + c1.w;
  float q = c0.x * c0.x + c0.y * c0.y + c0.z * c0.z + c0.w * c0.w +
            c1.x * c1.x + c1.y * c1.y + c1.z * c1.z + c1.w * c1.w;
#pragma unroll
  for (int o = 1; o < 64; o <<= 1) {
    s += __shfl_xor(s, o, 64);
    q += __shfl_xor(q, o, 64);
  }
  const float S1 = s, Q1 = q;

  const float4 g0 = *(const float4*)(gam + H_DIM + lane * 8);
  const float4 g1 = *(const float4*)(gam + H_DIM + lane * 8 + 4);
  const float4 e0 = *(const float4*)(bet + H_DIM + lane * 8);
  const float4 e1 = *(const float4*)(bet + H_DIM + lane * 8 + 4);

  float r[8];
#pragma unroll
  for (int i = 0; i < 8; ++i) r[i] = 0.f;

  const int sw = (lane & ~7) | ((lane & 7) ^ (b & 7));
  __bf16* arow = act2 + (size_t)b * H_DIM + sw * 8;

  for (int n = 0; n < N_F; ++n) {
    s = 0.f; q = 0.f;
#pragma unroll
    for (int i = 0; i < 8; ++i) { s += r[i]; q += r[i] * r[i]; }
#pragma unroll
    for (int o = 1; o < 64; o <<= 1) {
      s += __shfl_xor(s, o, 64);
      q += __shfl_xor(q, o, 64);
    }
    const float mean = (S1 + s) * (1.0f / 1024.0f);
    const float var = (Q1 + q) * (1.0f / 1024.0f) - mean * mean;
    const float rs = rsqrtf(var + 1e-5f);
    if (lane == 0)
      *(float2*)(stats + ((size_t)b * N_F + n) * 2) = make_float2(mean, rs);

    // issue next gather early so latency hides under the gelu work
    float4 t0, t1;
    const bool have = (n < N_F - 1);
    if (have) {
      const int f = feat[b * N_F + n];
      const float* tr = tab + ((size_t)n * V_DIM + f) * H_DIM + lane * 8;
      t0 = *(const float4*)tr;
      t1 = *(const float4*)(tr + 4);
    }

    bf16x8 pk;
    pk[0] = (__bf16)gelu_f((r[0] - mean) * rs * g0.x + e0.x);
    pk[1] = (__bf16)gelu_f((r[1] - mean) * rs * g0.y + e0.y);
    pk[2] = (__bf16)gelu_f((r[2] - mean) * rs * g0.z + e0.z);
    pk[3] = (__bf16)gelu_f((r[3] - mean) * rs * g0.w + e0.w);
    pk[4] = (__bf16)gelu_f((r[4] - mean) * rs * g1.x + e1.x);
    pk[5] = (__bf16)gelu_f((r[5] - mean) * rs * g1.y + e1.y);
    pk[6] = (__bf16)gelu_f((r[6] - mean) * rs * g1.z + e1.z);
    pk[7] = (__bf16)gelu_f((r[7] - mean) * rs * g1.w + e1.w);
    *(bf16x8*)(arow + (size_t)n * B_SZ * H_DIM) = pk;

    if (have) {
      r[0] += t0.x; r[1] += t0.y; r[2] += t0.z; r[3] += t0.w;
      r[4] += t1.x; r[5] += t1.y; r[6] += t1.z; r[7] += t1.w;
    }
  }
}

// ---------------------------------------------------------------------------
// Kernel 2: pred_W [N][K][V] fp32 -> Wt [N][V][K] bf16, chunk-swizzled by v&7
// so that gld staging in k_gemm lands conflict-free in LDS.
// ---------------------------------------------------------------------------
__global__ __launch_bounds__(256) void k_wt(const float* __restrict__ W,
                                            __bf16* __restrict__ Wt) {
  __shared__ float tile[32][33];
  const int bid = blockIdx.x;
  const int n = bid >> 8;
  const int rem = bid & 255;
  const int kt = rem >> 3, vt = rem & 7;
  const int tx = threadIdx.x & 31, ty = threadIdx.x >> 5;
  const float* src = W + (size_t)n * K_DIM * V_DIM;
#pragma unroll
  for (int i = 0; i < 4; ++i) {
    const int k = kt * 32 + ty + i * 8;
    tile[ty + i * 8][tx] = src[(size_t)k * V_DIM + vt * 32 + tx];
  }
  __syncthreads();
  __bf16* dst = Wt + (size_t)n * V_DIM * K_DIM;
  const int t = threadIdx.x;
  if (t < 128) {
    const int v_l = t >> 2, c_l = t & 3;
    const int v = vt * 32 + v_l;
    bf16x8 pk;
#pragma unroll
    for (int e = 0; e < 8; ++e) pk[e] = (__bf16)tile[c_l * 8 + e][v_l];
    const int gc = kt * 4 + c_l;
    const int swc = (gc & ~7) | ((gc & 7) ^ (v & 7));
    *(bf16x8*)(dst + (size_t)v * K_DIM + swc * 8) = pk;
  }
}

// ---------------------------------------------------------------------------
// Kernel 3: GEMM, single-barrier double-buffer (T3-min recipe).
// grid = (B/128, N), 512 threads (8 waves 2x4). BM=128 BN=256 BK=64.
// LDS 96 KB -> 1 block/CU, 2 waves/SIMD, VGPR budget 256.
// ctx half (kt<8): LN+GELU computed ONCE in prologue into 64 VGPRs
// (ctx[16] bf16x8), contributed per K-step via 2 swizzled ds_write_b128.
// masked half (kt>=8): act2 gld_lds as before.
// Per K-step: stage(next) first, compute(cur), ONE __syncthreads (its
// vmcnt(0)+lgkmcnt(0) drain guarantees next tile landed & writes visible).
// ---------------------------------------------------------------------------
__global__ __launch_bounds__(512, 2) void k_gemm(
    const float* __restrict__ ie, const __bf16* __restrict__ act2,
    const __bf16* __restrict__ Wt, const float* __restrict__ stats,
    const float* __restrict__ gam, const float* __restrict__ bet,
    const float* __restrict__ bias, float* __restrict__ out) {
  constexpr int BM = 128, BN = 256, BK = 64;
  __shared__ __align__(16) __bf16 As[2][BM * BK];  // 2 x 16 KB
  __shared__ __align__(16) __bf16 Ws[2][BN * BK];  // 2 x 32 KB (total 96 KB)

  const int n = blockIdx.y;
  const int b0 = blockIdx.x * BM;
  const int t = threadIdx.x;
  const int lane = t & 63;
  const int w = t >> 6;
  const int wm = w & 1;
  const int wn = w >> 1;
  const int l15 = lane & 15;
  const int lq = lane >> 4;
  const int lr8 = lane >> 3;
  const int lo8 = lane & 7;

  const __bf16* act2n = act2 + (size_t)n * B_SZ * H_DIM;
  const __bf16* Wtn = Wt + (size_t)n * V_DIM * K_DIM;

  // ---- stage W tile kt=0 first so its latency hides under the prologue ----
  {
    const int k0 = 0;
#pragma unroll
    for (int p = 0; p < 4; ++p) {
      const int v0 = w * 32 + p * 8;
      gld_lds16(Wtn + (size_t)(v0 + lr8) * K_DIM + k0 + lo8 * 8,
                &Ws[0][v0 * BK]);
    }
  }

  // ---- prologue: ctx -> regs, LN+GELU once. Thread t: row pr=t>>2,
  // col-quarter pm=t&3 -> logical chunks {2pm, 2pm+1} of each 64-col group.
  const int pr = t >> 2;
  const int pm = t & 3;
  bf16x8 ctx[16];
  {
    const float2 st = *(const float2*)(stats + ((size_t)(b0 + pr) * N_F + n) * 2);
    const float mu = st.x, rs = st.y;
    const float* ierow = ie + (size_t)(b0 + pr) * H_DIM;
#pragma unroll
    for (int k8 = 0; k8 < 8; ++k8) {
#pragma unroll
      for (int h = 0; h < 2; ++h) {
        const int col = k8 * 64 + pm * 16 + h * 8;
        const float4 x0 = *(const float4*)(ierow + col);
        const float4 x1 = *(const float4*)(ierow + col + 4);
        const float4 gg0 = *(const float4*)(gam + col);
        const float4 gg1 = *(const float4*)(gam + col + 4);
        const float4 bb0 = *(const float4*)(bet + col);
        const float4 bb1 = *(const float4*)(bet + col + 4);
        bf16x8 pk;
        pk[0] = (__bf16)gelu_f((x0.x - mu) * rs * gg0.x + bb0.x);
        pk[1] = (__bf16)gelu_f((x0.y - mu) * rs * gg0.y + bb0.y);
        pk[2] = (__bf16)gelu_f((x0.z - mu) * rs * gg0.z + bb0.z);
        pk[3] = (__bf16)gelu_f((x0.w - mu) * rs * gg0.w + bb0.w);
        pk[4] = (__bf16)gelu_f((x1.x - mu) * rs * gg1.x + bb1.x);
        pk[5] = (__bf16)gelu_f((x1.y - mu) * rs * gg1.y + bb1.y);
        pk[6] = (__bf16)gelu_f((x1.z - mu) * rs * gg1.z + bb1.z);
        pk[7] = (__bf16)gelu_f((x1.w - mu) * rs * gg1.w + bb1.w);
        ctx[k8 * 2 + h] = pk;
      }
    }
  }

  // swizzled LDS slots for this thread's two ctx chunks (constant per thread)
  const int sA0 = pr * BK + (((pm * 2) ^ (pr & 7)) << 3);
  const int sA1 = pr * BK + (((pm * 2 + 1) ^ (pr & 7)) << 3);

  f32x4 acc[4][4];
#pragma unroll
  for (int i = 0; i < 4; ++i)
#pragma unroll
    for (int j = 0; j < 4; ++j) acc[i][j] = (f32x4){0.f, 0.f, 0.f, 0.f};

  // A tile kt=0 from regs
  *(bf16x8*)(&As[0][sA0]) = ctx[0];
  *(bf16x8*)(&As[0][sA1]) = ctx[1];
  __syncthreads();

  int cur = 0;
#pragma unroll
  for (int kt = 0; kt < 16; ++kt) {
    // ---- stage tile kt+1 into buf cur^1 (issued BEFORE compute) ----
    if (kt < 15) {
      const int k0 = (kt + 1) * BK;
#pragma unroll
      for (int p = 0; p < 4; ++p) {
        const int v0 = w * 32 + p * 8;
        gld_lds16(Wtn + (size_t)(v0 + lr8) * K_DIM + k0 + lo8 * 8,
                  &Ws[cur ^ 1][v0 * BK]);
      }
      if (kt + 1 < 8) {
        *(bf16x8*)(&As[cur ^ 1][sA0]) = ctx[(kt + 1) * 2];
        *(bf16x8*)(&As[cur ^ 1][sA1]) = ctx[(kt + 1) * 2 + 1];
      } else {
#pragma unroll
        for (int p = 0; p < 2; ++p) {
          const int r0 = w * 16 + p * 8;
          gld_lds16(act2n + (size_t)(b0 + r0 + lr8) * H_DIM + (k0 - H_DIM) + lo8 * 8,
                    &As[cur ^ 1][r0 * BK]);
        }
      }
    }
    // ---- compute tile kt from buf cur ----
#pragma unroll
    for (int ks = 0; ks < 2; ++ks) {
      const int cs = ks * 4 + lq;
      bf16x8 af[4], bb[4];
#pragma unroll
      for (int i = 0; i < 4; ++i) {
        const int row = wm * 64 + i * 16 + l15;
        af[i] = *(const bf16x8*)(&As[cur][row * BK + ((cs ^ (row & 7)) << 3)]);
      }
#pragma unroll
      for (int j = 0; j < 4; ++j) {
        const int row = wn * 64 + j * 16 + l15;
        bb[j] = *(const bf16x8*)(&Ws[cur][row * BK + ((cs ^ (row & 7)) << 3)]);
      }
#pragma unroll
      for (int i = 0; i < 4; ++i)
#pragma unroll
        for (int j = 0; j < 4; ++j)
          acc[i][j] = __builtin_amdgcn_mfma_f32_16x16x32_bf16(af[i], bb[j],
                                                              acc[i][j], 0, 0, 0);
    }
    __syncthreads();  // vmcnt(0)+lgkmcnt(0)+barrier: tile kt+1 ready
    cur ^= 1;
  }

  // epilogue: C/D layout col=lane&15, row=(lane>>4)*4+reg
#pragma unroll
  for (int j = 0; j < 4; ++j) {
    const int v = wn * 64 + j * 16 + l15;
    const float bv = bias[n * V_DIM + v];
#pragma unroll
    for (int i = 0; i < 4; ++i) {
      const int rb = wm * 64 + i * 16 + lq * 4;
#pragma unroll
      for (int r = 0; r < 4; ++r) {
        out[((size_t)(b0 + rb + r) * N_F + n) * V_DIM + v] = acc[i][j][r] + bv;
      }
    }
  }
}

// ---------------------------------------------------------------------------
extern "C" void kernel_launch(void* const* d_in, const int* in_sizes, int n_in,
                              void* d_out, int out_size, void* d_ws, size_t ws_size,
                              hipStream_t stream) {
  const float* ie = (const float*)d_in[0];
  const int* feat = (const int*)d_in[1];
  const float* tab = (const float*)d_in[2];
  const float* gam = (const float*)d_in[3];
  const float* bet = (const float*)d_in[4];
  const float* predW = (const float*)d_in[5];
  const float* predb = (const float*)d_in[6];
  float* out = (float*)d_out;

  char* ws = (char*)d_ws;
  __bf16* act2 = (__bf16*)ws;                        // 100,663,296 B
  float* stats = (float*)(ws + 100663296);           //     786,432 B
  __bf16* Wt = (__bf16*)(ws + 100663296 + 786432);   //   6,291,456 B

  hipLaunchKernelGGL(k_prep, dim3(B_SZ / 4), dim3(256), 0, stream, ie, feat,
                     tab, gam, bet, act2, stats);
  hipLaunchKernelGGL(k_wt, dim3(3072), dim3(256), 0, stream, predW, Wt);
  hipLaunchKernelGGL(k_gemm, dim3(B_SZ / 128, N_F), dim3(512), 0, stream, ie,
                     act2, Wt, stats, gam, bet, predb, out);
}